// Round 3
// baseline (560.544 us; speedup 1.0000x reference)
//
#include <hip/hip_runtime.h>
#include <hip/hip_bf16.h>
#include <stdint.h>

// Problem: B=8, N=2048, D_IN=D_ATT=512. Inputs/outputs are FLOAT32 per the
// reference; internal compute uses bf16 MFMA with fp32 accumulate.
#define BB 8
#define NN 2048
#define DD 512

typedef unsigned short u16;
typedef __attribute__((ext_vector_type(8))) short bf16x8;     // MFMA A/B frag
typedef __attribute__((ext_vector_type(8))) unsigned short u16x8;
typedef __attribute__((ext_vector_type(4))) float f32x4;      // MFMA C/D frag

__device__ __forceinline__ u16 f2b(float f) {   // RNE f32 -> bf16
  unsigned int u;
  __builtin_memcpy(&u, &f, 4);
  u += 0x7fffu + ((u >> 16) & 1u);
  return (u16)(u >> 16);
}

// ---------------------------------------------------------------------------
// TN GEMM: C[m,n] = alpha * sum_k A[m,k]*Bt[n,k] (+ bias[n]).
// A: f32 (converted during staging) if AF32, else bf16. Bt: always bf16.
// C: f32 if CF32 else bf16. TRANSC: write C as Ct[b][n][i] (bf16 only).
// 128x128 tile, BK=64, 256 threads, plain ds_write staging (correctness-first).
// ---------------------------------------------------------------------------
template<bool AF32, bool BIAS, bool TRANSC, bool CF32>
__global__ __launch_bounds__(256, 2)
void gemm_tn(const void* __restrict__ A_, const u16* __restrict__ Bt,
             const float* __restrict__ bias, void* __restrict__ C_,
             int N, int K, float alpha,
             long long sAb, long long sBb, long long sCb)
{
  __shared__ __align__(16) u16 sA[128 * 64];
  __shared__ __align__(16) u16 sB[128 * 64];
  const int tid  = threadIdx.x;
  const int wave = tid >> 6;
  const int lane = tid & 63;
  const int m0 = blockIdx.y * 128;
  const int n0 = blockIdx.x * 128;
  const long long bz = blockIdx.z;

  const float* Af = (const float*)A_ + (AF32 ? bz * sAb : 0);
  const u16*   Ab = (const u16*)A_ + (AF32 ? 0 : bz * sAb);
  Bt += bz * sBb;
  float* Cf = (float*)C_ + (CF32 ? bz * sCb : 0);
  u16*   Cb = (u16*)C_ + (CF32 ? 0 : bz * sCb);

  // staging coords: round r covers tile row r*32 + wave*8 + (lane>>3),
  // tile cols (lane&7)*8 .. +7
  const int srow = wave * 8 + (lane >> 3);
  const int scol = (lane & 7) * 8;

  f32x4 acc[4][4];
#pragma unroll
  for (int i = 0; i < 4; ++i)
#pragma unroll
    for (int j = 0; j < 4; ++j) {
      f32x4 z = {0.f, 0.f, 0.f, 0.f};
      acc[i][j] = z;
    }

  const int wm  = (wave & 1) * 64;   // wave's 64x64 sub-tile
  const int wn  = (wave >> 1) * 64;
  const int l15 = lane & 15;
  const int qk  = (lane >> 4) * 8;   // quad k-offset within 32

  for (int k0 = 0; k0 < K; k0 += 64) {
#pragma unroll
    for (int r = 0; r < 4; ++r) {
      const int row = r * 32 + srow;
      // A tile
      if (AF32) {
        const float* g = Af + (long long)(m0 + row) * K + k0 + scol;
        const float4 a0 = *(const float4*)g;
        const float4 a1 = *(const float4*)(g + 4);
        u16x8 p;
        p[0] = f2b(a0.x); p[1] = f2b(a0.y); p[2] = f2b(a0.z); p[3] = f2b(a0.w);
        p[4] = f2b(a1.x); p[5] = f2b(a1.y); p[6] = f2b(a1.z); p[7] = f2b(a1.w);
        *(u16x8*)(sA + row * 64 + scol) = p;
      } else {
        *(u16x8*)(sA + row * 64 + scol) =
            *(const u16x8*)(Ab + (long long)(m0 + row) * K + k0 + scol);
      }
      // B tile (always bf16)
      *(u16x8*)(sB + row * 64 + scol) =
          *(const u16x8*)(Bt + (long long)(n0 + row) * K + k0 + scol);
    }
    __syncthreads();
#pragma unroll
    for (int kk = 0; kk < 64; kk += 32) {
      bf16x8 af[4], bg[4];
#pragma unroll
      for (int mt = 0; mt < 4; ++mt)
        af[mt] = *(const bf16x8*)(sA + (wm + mt * 16 + l15) * 64 + kk + qk);
#pragma unroll
      for (int nt = 0; nt < 4; ++nt)
        bg[nt] = *(const bf16x8*)(sB + (wn + nt * 16 + l15) * 64 + kk + qk);
#pragma unroll
      for (int mt = 0; mt < 4; ++mt)
#pragma unroll
        for (int nt = 0; nt < 4; ++nt)
          acc[mt][nt] = __builtin_amdgcn_mfma_f32_16x16x32_bf16(
              af[mt], bg[nt], acc[mt][nt], 0, 0, 0);
    }
    __syncthreads();
  }

  // C/D layout: col = lane&15, row = (lane>>4)*4 + reg  [m89/m91 verified]
  const int rowq = (lane >> 4) * 4;
#pragma unroll
  for (int nt = 0; nt < 4; ++nt) {
    const int gn = n0 + wn + nt * 16 + l15;
    const float bval = BIAS ? bias[gn] : 0.f;
#pragma unroll
    for (int mt = 0; mt < 4; ++mt) {
      if (TRANSC) {
        // 4 consecutive m-rows are contiguous in Ct[b][gn][i] -> one 8B store
        const int gm = m0 + wm + mt * 16 + rowq;
        const int b  = gm >> 11;
        const int i  = gm & (NN - 1);
        ushort4 pk;
        pk.x = f2b(acc[mt][nt][0] * alpha + bval);
        pk.y = f2b(acc[mt][nt][1] * alpha + bval);
        pk.z = f2b(acc[mt][nt][2] * alpha + bval);
        pk.w = f2b(acc[mt][nt][3] * alpha + bval);
        *(ushort4*)(&Cb[((long long)b * DD + gn) * NN + i]) = pk;
      } else {
#pragma unroll
        for (int r = 0; r < 4; ++r) {
          const int gm = m0 + wm + mt * 16 + rowq + r;
          const float v = acc[mt][nt][r] * alpha + bval;
          if (CF32) Cf[(long long)gm * N + gn] = v;
          else      Cb[(long long)gm * N + gn] = f2b(v);
        }
      }
    }
  }
}

// ---------------------------------------------------------------------------
// f32 -> bf16 bulk convert (x)
// ---------------------------------------------------------------------------
__global__ __launch_bounds__(256)
void conv_f32_bf16(const float* __restrict__ in, u16* __restrict__ out)
{
  const long long i = ((long long)blockIdx.x * 256 + threadIdx.x) * 4;
  const float4 v = *(const float4*)(in + i);
  ushort4 o;
  o.x = f2b(v.x); o.y = f2b(v.y); o.z = f2b(v.z); o.w = f2b(v.w);
  *(ushort4*)(out + i) = o;
}

// ---------------------------------------------------------------------------
// 64x64 transpose + f32->bf16 convert (for the 512x512 weight matrices)
// ---------------------------------------------------------------------------
__global__ __launch_bounds__(256)
void transpose_conv(const float* __restrict__ in, u16* __restrict__ out)
{
  __shared__ float tile[64][65];
  const int r0 = blockIdx.y * 64;
  const int c0 = blockIdx.x * 64;
  const int tr = threadIdx.x >> 6;
  const int tc = threadIdx.x & 63;
#pragma unroll
  for (int k = 0; k < 16; ++k) {
    const int r = k * 4 + tr;
    tile[r][tc] = in[(long long)(r0 + r) * 512 + c0 + tc];
  }
  __syncthreads();
#pragma unroll
  for (int k = 0; k < 16; ++k) {
    const int r = k * 4 + tr;
    out[(long long)(c0 + r) * 512 + r0 + tc] = f2b(tile[tc][r]);
  }
}

// ---------------------------------------------------------------------------
// Column softmax (axis=1 -> over rows i) on f32 S[b][i][j], in place.
// ---------------------------------------------------------------------------
__global__ __launch_bounds__(256)
void softmax_stats_partial(const float* __restrict__ S,
                           float* __restrict__ pm, float* __restrict__ pl)
{
  const int j  = blockIdx.x * 256 + threadIdx.x;  // column
  const int ch = blockIdx.y;                      // 256-row chunk
  const int b  = blockIdx.z;
  const float* p = S + ((long long)b * NN + ch * 256) * NN + j;
  float m = -3.4e38f;
  for (int i = 0; i < 256; ++i)
    m = fmaxf(m, p[(long long)i * NN]);
  float l = 0.f;
  for (int i = 0; i < 256; ++i)
    l += __expf(p[(long long)i * NN] - m);
  const long long idx = ((long long)b * 8 + ch) * NN + j;
  pm[idx] = m;
  pl[idx] = l;
}

__global__ __launch_bounds__(256)
void softmax_stats_combine(const float* __restrict__ pm,
                           const float* __restrict__ pl,
                           float* __restrict__ cst)
{
  const int idx = blockIdx.x * 256 + threadIdx.x;  // b*2048 + j
  const int b = idx >> 11;
  const int j = idx & (NN - 1);
  float m = -3.4e38f;
#pragma unroll
  for (int c = 0; c < 8; ++c)
    m = fmaxf(m, pm[((long long)b * 8 + c) * NN + j]);
  float l = 0.f;
#pragma unroll
  for (int c = 0; c < 8; ++c)
    l += pl[((long long)b * 8 + c) * NN + j] *
         __expf(pm[((long long)b * 8 + c) * NN + j] - m);
  cst[idx] = m + __logf(l);   // w = exp(s - cst[j]) : one exp, no divide
}

__global__ __launch_bounds__(256)
void softmax_normalize(float* __restrict__ W, const float* __restrict__ cst)
{
  const long long idx = ((long long)blockIdx.x * 256 + threadIdx.x) * 4;
  const int b  = (int)(idx >> 22);          // / (2048*2048)
  const int j0 = (int)(idx & (NN - 1));     // 4 consecutive j, same row
  const float* c = cst + b * NN + j0;
  float4 v = *(float4*)(W + idx);
  v.x = __expf(v.x - c[0]);
  v.y = __expf(v.y - c[1]);
  v.z = __expf(v.z - c[2]);
  v.w = __expf(v.w - c[3]);
  *(float4*)(W + idx) = v;
}

// ---------------------------------------------------------------------------
extern "C" void kernel_launch(void* const* d_in, const int* in_sizes, int n_in,
                              void* d_out, int out_size, void* d_ws, size_t ws_size,
                              hipStream_t stream)
{
  const float* x  = (const float*)d_in[0];
  const float* Wq = (const float*)d_in[1];
  const float* bq = (const float*)d_in[2];
  const float* Wk = (const float*)d_in[3];
  const float* bk = (const float*)d_in[4];
  const float* Wv = (const float*)d_in[5];
  const float* bv = (const float*)d_in[6];

  float* outf = (float*)d_out;                         // [8][2048][512] f32
  float* Wf   = outf + (long long)BB * NN * DD;        // [8][2048][2048] f32

  // Q/K bf16 scratch lives inside the f32 out region (16.8M u16 = 33.5 MB):
  // dead before the final PV GEMM overwrites outf.
  u16* Qb = (u16*)d_out;                               // [8][2048][512] bf16
  u16* Kb = Qb + (long long)BB * NN * DD;

  // workspace carve (~36 MiB)
  u16* xb  = (u16*)d_ws;                               // [16384][512] bf16
  u16* WqT = xb + (long long)BB * NN * DD;             // [512][512] bf16 each
  u16* WkT = WqT + 512 * 512;
  u16* WvT = WkT + 512 * 512;
  u16* VTb = WvT + 512 * 512;                          // [8][512][2048] bf16
  float* pm  = (float*)(VTb + (long long)BB * NN * DD);
  float* pl  = pm + 8 * 8 * NN;
  float* cst = pl + 8 * 8 * NN;                        // [8][2048]

  dim3 blk(256);

  // x -> bf16; W -> transposed bf16 [e][d]
  conv_f32_bf16<<<dim3(8192), blk, 0, stream>>>(x, xb);
  transpose_conv<<<dim3(8, 8), blk, 0, stream>>>(Wq, WqT);
  transpose_conv<<<dim3(8, 8), blk, 0, stream>>>(Wk, WkT);
  transpose_conv<<<dim3(8, 8), blk, 0, stream>>>(Wv, WvT);

  // QKV projections: [16384,512] x [512,512] + bias -> bf16
  gemm_tn<false, true, false, false><<<dim3(4, 128, 1), blk, 0, stream>>>(
      xb, WqT, bq, Qb, 512, 512, 1.f, 0, 0, 0);
  gemm_tn<false, true, false, false><<<dim3(4, 128, 1), blk, 0, stream>>>(
      xb, WkT, bk, Kb, 512, 512, 1.f, 0, 0, 0);
  // V projection writes V^T directly: VTb[b][e][i]
  gemm_tn<false, true, true, false><<<dim3(4, 128, 1), blk, 0, stream>>>(
      xb, WvT, bv, VTb, 512, 512, 1.f, 0, 0, 0);

  // S = scale * Q K^T -> f32 weights region (normalized in place)
  const float scale = 0.044194173824159216f;  // 1/sqrt(512)
  gemm_tn<false, false, false, true><<<dim3(16, 16, 8), blk, 0, stream>>>(
      Qb, Kb, nullptr, Wf, NN, 512, scale,
      (long long)NN * DD, (long long)NN * DD, (long long)NN * NN);

  // column softmax over i (axis=1)
  softmax_stats_partial<<<dim3(8, 8, 8), blk, 0, stream>>>(Wf, pm, pl);
  softmax_stats_combine<<<dim3(64), blk, 0, stream>>>(pm, pl, cst);
  softmax_normalize<<<dim3(32768), blk, 0, stream>>>(Wf, cst);

  // out = weights x V : [2048,2048] x [2048,512] per batch, f32 A staged->bf16
  gemm_tn<true, false, false, true><<<dim3(4, 16, 8), blk, 0, stream>>>(
      Wf, VTb, nullptr, outf, DD, NN, 1.f,
      (long long)NN * NN, (long long)DD * NN, (long long)NN * DD);
}

// Round 4
// 503.771 us; speedup vs baseline: 1.1127x; 1.1127x over previous
//
#include <hip/hip_runtime.h>
#include <hip/hip_bf16.h>
#include <stdint.h>

// B=8, N=2048, D_IN=D_ATT=512. f32 in/out; bf16 MFMA internals (fp32 accum).
#define BB 8
#define NN 2048
#define DD 512

typedef unsigned short u16;
typedef __attribute__((ext_vector_type(8))) short bf16x8;     // MFMA A/B frag
typedef __attribute__((ext_vector_type(8))) unsigned short u16x8;
typedef __attribute__((ext_vector_type(4))) float f32x4;      // MFMA C/D frag

__device__ __forceinline__ u16 f2b(float f) {   // RNE f32 -> bf16
  unsigned int u;
  __builtin_memcpy(&u, &f, 4);
  u += 0x7fffu + ((u >> 16) & 1u);
  return (u16)(u >> 16);
}

// async global->LDS, 16B/lane; LDS dest = wave-uniform base, HW adds lane*16
__device__ __forceinline__ void glds16(const u16* g, u16* l) {
  __builtin_amdgcn_global_load_lds(
      (const __attribute__((address_space(1))) unsigned int*)g,
      (__attribute__((address_space(3))) unsigned int*)l, 16, 0, 0);
}

// ---------------------------------------------------------------------------
// Combined QKV GEMM: C[m,n] = sum_k x[m,k]*WT[n,k] + bias[n]
// M=16384, N=1536 (Q|K|V), K=512. A: f32 stage-converted; B: bf16 via glds16.
// Epilogue routes by n: [0,512)->Qb, [512,1024)->Kb, [1024,1536)->VTb (transposed).
// 128x128 tile, BK=64, 256 threads.
// ---------------------------------------------------------------------------
__global__ __launch_bounds__(256, 2)
void gemm_qkv(const float* __restrict__ x, const u16* __restrict__ WT,
              const float* __restrict__ bq, const float* __restrict__ bk,
              const float* __restrict__ bv,
              u16* __restrict__ Qb, u16* __restrict__ Kb, u16* __restrict__ VTb)
{
  __shared__ __align__(16) u16 sA[128 * 64];
  __shared__ __align__(16) u16 sB[128 * 64];
  const int tid  = threadIdx.x;
  const int wave = tid >> 6;
  const int lane = tid & 63;
  const int m0 = blockIdx.y * 128;
  const int n0 = blockIdx.x * 128;

  const int srow = wave * 8 + (lane >> 3);   // staging row within 32-row round
  const int scol = (lane & 7) * 8;           // staging col (8 elems)

  // B staging via glds16: lane covers row wave*8+(lane>>3), cols (lane&7)*8..+7
  const u16* gB = WT + (long long)(n0 + srow) * 512 + scol;
  u16* lB = sB + wave * 512;

  f32x4 acc[4][4];
#pragma unroll
  for (int i = 0; i < 4; ++i)
#pragma unroll
    for (int j = 0; j < 4; ++j) {
      f32x4 z = {0.f, 0.f, 0.f, 0.f};
      acc[i][j] = z;
    }

  const int wm  = (wave & 1) * 64;
  const int wn  = (wave >> 1) * 64;
  const int l15 = lane & 15;
  const int qk  = (lane >> 4) * 8;

  for (int k0 = 0; k0 < 512; k0 += 64) {
#pragma unroll
    for (int r = 0; r < 4; ++r) {
      glds16(gB + (long long)(r * 32) * 512 + k0, lB + r * 2048);
      // A: f32 -> bf16 convert during staging
      const int row = r * 32 + srow;
      const float* g = x + (long long)(m0 + row) * 512 + k0 + scol;
      const float4 a0 = *(const float4*)g;
      const float4 a1 = *(const float4*)(g + 4);
      u16x8 p;
      p[0] = f2b(a0.x); p[1] = f2b(a0.y); p[2] = f2b(a0.z); p[3] = f2b(a0.w);
      p[4] = f2b(a1.x); p[5] = f2b(a1.y); p[6] = f2b(a1.z); p[7] = f2b(a1.w);
      *(u16x8*)(sA + row * 64 + scol) = p;
    }
    __syncthreads();
#pragma unroll
    for (int kk = 0; kk < 64; kk += 32) {
      bf16x8 af[4], bg[4];
#pragma unroll
      for (int mt = 0; mt < 4; ++mt)
        af[mt] = *(const bf16x8*)(sA + (wm + mt * 16 + l15) * 64 + kk + qk);
#pragma unroll
      for (int nt = 0; nt < 4; ++nt)
        bg[nt] = *(const bf16x8*)(sB + (wn + nt * 16 + l15) * 64 + kk + qk);
#pragma unroll
      for (int mt = 0; mt < 4; ++mt)
#pragma unroll
        for (int nt = 0; nt < 4; ++nt)
          acc[mt][nt] = __builtin_amdgcn_mfma_f32_16x16x32_bf16(
              af[mt], bg[nt], acc[mt][nt], 0, 0, 0);
    }
    __syncthreads();
  }

  // C/D layout: col = lane&15, row = (lane>>4)*4 + reg
  const int rowq = (lane >> 4) * 4;
  const int route = n0 >> 9;                 // block-uniform (128 | 512)
  const float* bp = (route == 0) ? bq : (route == 1) ? bk : bv;
#pragma unroll
  for (int nt = 0; nt < 4; ++nt) {
    const int gn = n0 + wn + nt * 16 + l15;
    const int ln = gn & 511;
    const float bval = bp[ln];
#pragma unroll
    for (int mt = 0; mt < 4; ++mt) {
      const int gm = m0 + wm + mt * 16 + rowq;
      if (route == 2) {
        // V^T: rows gm..gm+3 contiguous in VTb[b][ln][i] -> one 8B store
        const int b = gm >> 11;
        const int i = gm & (NN - 1);
        ushort4 pk;
        pk.x = f2b(acc[mt][nt][0] + bval);
        pk.y = f2b(acc[mt][nt][1] + bval);
        pk.z = f2b(acc[mt][nt][2] + bval);
        pk.w = f2b(acc[mt][nt][3] + bval);
        *(ushort4*)(&VTb[((long long)b * DD + ln) * NN + i]) = pk;
      } else {
        u16* Cb = (route == 0) ? Qb : Kb;
#pragma unroll
        for (int r = 0; r < 4; ++r)
          Cb[(long long)(gm + r) * DD + ln] = f2b(acc[mt][nt][r] + bval);
      }
    }
  }
}

// ---------------------------------------------------------------------------
// bf16 TN GEMM, glds16 both operands: C[m,n] = alpha * sum_k A[m,k]*Bt[n,k]
// C written f32. 128x128 tile, BK=64, 256 threads. Batched via blockIdx.z.
// ---------------------------------------------------------------------------
__global__ __launch_bounds__(256, 2)
void gemm_bf16(const u16* __restrict__ A, const u16* __restrict__ Bt,
               float* __restrict__ C, int N, int K, float alpha,
               long long sAb, long long sBb, long long sCb)
{
  __shared__ __align__(16) u16 sA[128 * 64];
  __shared__ __align__(16) u16 sB[128 * 64];
  const int tid  = threadIdx.x;
  const int wave = tid >> 6;
  const int lane = tid & 63;
  const int m0 = blockIdx.y * 128;
  const int n0 = blockIdx.x * 128;
  const long long bz = blockIdx.z;
  A  += bz * sAb;
  Bt += bz * sBb;
  C  += bz * sCb;

  const int srow = wave * 8 + (lane >> 3);
  const int scol = (lane & 7) * 8;
  const u16* gA = A  + (long long)(m0 + srow) * K + scol;
  const u16* gB = Bt + (long long)(n0 + srow) * K + scol;
  u16* lA = sA + wave * 512;
  u16* lB = sB + wave * 512;

  f32x4 acc[4][4];
#pragma unroll
  for (int i = 0; i < 4; ++i)
#pragma unroll
    for (int j = 0; j < 4; ++j) {
      f32x4 z = {0.f, 0.f, 0.f, 0.f};
      acc[i][j] = z;
    }

  const int wm  = (wave & 1) * 64;
  const int wn  = (wave >> 1) * 64;
  const int l15 = lane & 15;
  const int qk  = (lane >> 4) * 8;

  for (int k0 = 0; k0 < K; k0 += 64) {
#pragma unroll
    for (int r = 0; r < 4; ++r) {
      glds16(gA + (long long)(r * 32) * K + k0, lA + r * 2048);
      glds16(gB + (long long)(r * 32) * K + k0, lB + r * 2048);
    }
    __syncthreads();
#pragma unroll
    for (int kk = 0; kk < 64; kk += 32) {
      bf16x8 af[4], bg[4];
#pragma unroll
      for (int mt = 0; mt < 4; ++mt)
        af[mt] = *(const bf16x8*)(sA + (wm + mt * 16 + l15) * 64 + kk + qk);
#pragma unroll
      for (int nt = 0; nt < 4; ++nt)
        bg[nt] = *(const bf16x8*)(sB + (wn + nt * 16 + l15) * 64 + kk + qk);
#pragma unroll
      for (int mt = 0; mt < 4; ++mt)
#pragma unroll
        for (int nt = 0; nt < 4; ++nt)
          acc[mt][nt] = __builtin_amdgcn_mfma_f32_16x16x32_bf16(
              af[mt], bg[nt], acc[mt][nt], 0, 0, 0);
    }
    __syncthreads();
  }

  const int rowq = (lane >> 4) * 4;
#pragma unroll
  for (int nt = 0; nt < 4; ++nt) {
    const int gn = n0 + wn + nt * 16 + l15;
#pragma unroll
    for (int mt = 0; mt < 4; ++mt) {
#pragma unroll
      for (int r = 0; r < 4; ++r) {
        const int gm = m0 + wm + mt * 16 + rowq + r;
        C[(long long)gm * N + gn] = acc[mt][nt][r] * alpha;
      }
    }
  }
}

// ---------------------------------------------------------------------------
// 64x64 transpose + f32->bf16 (512x512 weight matrices into WT at row offset)
// ---------------------------------------------------------------------------
__global__ __launch_bounds__(256)
void transpose_conv(const float* __restrict__ in, u16* __restrict__ out)
{
  __shared__ float tile[64][65];
  const int r0 = blockIdx.y * 64;
  const int c0 = blockIdx.x * 64;
  const int tr = threadIdx.x >> 6;
  const int tc = threadIdx.x & 63;
#pragma unroll
  for (int k = 0; k < 16; ++k) {
    const int r = k * 4 + tr;
    tile[r][tc] = in[(long long)(r0 + r) * 512 + c0 + tc];
  }
  __syncthreads();
#pragma unroll
  for (int k = 0; k < 16; ++k) {
    const int r = k * 4 + tr;
    out[(long long)(c0 + r) * 512 + r0 + tc] = f2b(tile[tc][r]);
  }
}

// ---------------------------------------------------------------------------
// Column softmax (axis=1 -> over rows i) on f32 S[b][i][j].
// ---------------------------------------------------------------------------
__global__ __launch_bounds__(256)
void softmax_stats_partial(const float* __restrict__ S,
                           float* __restrict__ pm, float* __restrict__ pl)
{
  const int j  = blockIdx.x * 256 + threadIdx.x;
  const int ch = blockIdx.y;
  const int b  = blockIdx.z;
  const float* p = S + ((long long)b * NN + ch * 256) * NN + j;
  float m = -3.4e38f;
  for (int i = 0; i < 256; ++i)
    m = fmaxf(m, p[(long long)i * NN]);
  float l = 0.f;
  for (int i = 0; i < 256; ++i)
    l += __expf(p[(long long)i * NN] - m);
  const long long idx = ((long long)b * 8 + ch) * NN + j;
  pm[idx] = m;
  pl[idx] = l;
}

__global__ __launch_bounds__(256)
void softmax_stats_combine(const float* __restrict__ pm,
                           const float* __restrict__ pl,
                           float* __restrict__ cst)
{
  const int idx = blockIdx.x * 256 + threadIdx.x;  // b*2048 + j
  const int b = idx >> 11;
  const int j = idx & (NN - 1);
  float m = -3.4e38f;
#pragma unroll
  for (int c = 0; c < 8; ++c)
    m = fmaxf(m, pm[((long long)b * 8 + c) * NN + j]);
  float l = 0.f;
#pragma unroll
  for (int c = 0; c < 8; ++c)
    l += pl[((long long)b * 8 + c) * NN + j] *
         __expf(pm[((long long)b * 8 + c) * NN + j] - m);
  cst[idx] = m + __logf(l);   // w = exp(s - cst[j])
}

// in-place f32 normalize + bf16 copy for the PV GEMM
__global__ __launch_bounds__(256)
void softmax_normalize(float* __restrict__ W, u16* __restrict__ Wb,
                       const float* __restrict__ cst)
{
  const long long idx = ((long long)blockIdx.x * 256 + threadIdx.x) * 4;
  const int b  = (int)(idx >> 22);
  const int j0 = (int)(idx & (NN - 1));
  const float* c = cst + b * NN + j0;
  float4 v = *(float4*)(W + idx);
  v.x = __expf(v.x - c[0]);
  v.y = __expf(v.y - c[1]);
  v.z = __expf(v.z - c[2]);
  v.w = __expf(v.w - c[3]);
  *(float4*)(W + idx) = v;
  ushort4 o;
  o.x = f2b(v.x); o.y = f2b(v.y); o.z = f2b(v.z); o.w = f2b(v.w);
  *(ushort4*)(Wb + idx) = o;
}

// ---------------------------------------------------------------------------
extern "C" void kernel_launch(void* const* d_in, const int* in_sizes, int n_in,
                              void* d_out, int out_size, void* d_ws, size_t ws_size,
                              hipStream_t stream)
{
  const float* x  = (const float*)d_in[0];
  const float* Wq = (const float*)d_in[1];
  const float* bq = (const float*)d_in[2];
  const float* Wk = (const float*)d_in[3];
  const float* bk = (const float*)d_in[4];
  const float* Wv = (const float*)d_in[5];
  const float* bv = (const float*)d_in[6];

  float* outf = (float*)d_out;                         // [8][2048][512] f32
  float* Wf   = outf + (long long)BB * NN * DD;        // [8][2048][2048] f32

  // Q/K bf16 scratch inside the f32 out region (dead before PV writes outf)
  u16* Qb = (u16*)d_out;                               // [8][2048][512] bf16
  u16* Kb = Qb + (long long)BB * NN * DD;

  // workspace carve (~86.5 MiB)
  u16* Wb  = (u16*)d_ws;                               // [8][2048][2048] bf16
  u16* VTb = Wb + (long long)BB * NN * NN;             // [8][512][2048] bf16
  u16* WT  = VTb + (long long)BB * NN * DD;            // [1536][512] bf16
  float* pm  = (float*)(WT + 1536 * 512);              // [8][8][2048]
  float* pl  = pm + 8 * 8 * NN;
  float* cst = pl + 8 * 8 * NN;                        // [8][2048]

  dim3 blk(256);

  // W^T (bf16) concatenated: rows [0,512)=Wq^T, [512,1024)=Wk^T, [1024,1536)=Wv^T
  transpose_conv<<<dim3(8, 8), blk, 0, stream>>>(Wq, WT);
  transpose_conv<<<dim3(8, 8), blk, 0, stream>>>(Wk, WT + 512 * 512);
  transpose_conv<<<dim3(8, 8), blk, 0, stream>>>(Wv, WT + 2 * 512 * 512);

  // fused QKV projection: [16384,512] x [512,1536] + bias
  gemm_qkv<<<dim3(12, 128), blk, 0, stream>>>(x, WT, bq, bk, bv, Qb, Kb, VTb);

  // S = scale * Q K^T -> f32 weights region
  const float scale = 0.044194173824159216f;  // 1/sqrt(512)
  gemm_bf16<<<dim3(16, 16, 8), blk, 0, stream>>>(Qb, Kb, Wf, NN, 512, scale,
      (long long)NN * DD, (long long)NN * DD, (long long)NN * NN);

  // column softmax over i (axis=1); normalize writes f32 output + bf16 copy
  softmax_stats_partial<<<dim3(8, 8, 8), blk, 0, stream>>>(Wf, pm, pl);
  softmax_stats_combine<<<dim3(64), blk, 0, stream>>>(pm, pl, cst);
  softmax_normalize<<<dim3(32768), blk, 0, stream>>>(Wf, Wb, cst);

  // out = weights x V : [2048,2048] x [2048,512] per batch (bf16 operands)
  gemm_bf16<<<dim3(4, 16, 8), blk, 0, stream>>>(Wb, VTb, outf, DD, NN, 1.f,
      (long long)NN * NN, (long long)DD * NN, (long long)NN * DD);
}

// Round 5
// 409.161 us; speedup vs baseline: 1.3700x; 1.2312x over previous
//
#include <hip/hip_runtime.h>
#include <hip/hip_bf16.h>
#include <stdint.h>

// B=8, N=2048, D_IN=D_ATT=512. f32 in/out; bf16 MFMA internals (fp32 accum).
#define BB 8
#define NN 2048
#define DD 512

typedef unsigned short u16;
typedef __attribute__((ext_vector_type(8))) short bf16x8;     // MFMA A/B frag
typedef __attribute__((ext_vector_type(8))) unsigned short u16x8;
typedef __attribute__((ext_vector_type(4))) float f32x4;      // MFMA C/D frag

__device__ __forceinline__ float b2f(u16 h) {
  unsigned int u = ((unsigned int)h) << 16;
  float f;
  __builtin_memcpy(&f, &u, 4);
  return f;
}
__device__ __forceinline__ u16 f2b(float f) {   // RNE f32 -> bf16
  unsigned int u;
  __builtin_memcpy(&u, &f, 4);
  u += 0x7fffu + ((u >> 16) & 1u);
  return (u16)(u >> 16);
}

// async global->LDS, 16B/lane; LDS dest = wave-uniform base, HW adds lane*16
__device__ __forceinline__ void glds16(const u16* g, u16* l) {
  __builtin_amdgcn_global_load_lds(
      (const __attribute__((address_space(1))) unsigned int*)g,
      (__attribute__((address_space(3))) unsigned int*)l, 16, 0, 0);
}

// ---------------------------------------------------------------------------
// Fused QKV GEMM: C[m,n] = sum_k xb[m,k]*WT[n,k] + bias[n]; all bf16 glds16.
// M=16384, N=1536 (Q|K|V), K=512. Epilogue routes: n<512->Qb, <1024->Kb,
// >=1024 -> VTb transposed. 128x128 tile, BK=64, 256 threads.
// ---------------------------------------------------------------------------
__global__ __launch_bounds__(256, 2)
void gemm_qkv(const u16* __restrict__ xb, const u16* __restrict__ WT,
              const float* __restrict__ bq, const float* __restrict__ bk,
              const float* __restrict__ bv,
              u16* __restrict__ Qb, u16* __restrict__ Kb, u16* __restrict__ VTb)
{
  __shared__ __align__(16) u16 sA[128 * 64];
  __shared__ __align__(16) u16 sB[128 * 64];
  const int tid  = threadIdx.x;
  const int wave = tid >> 6;
  const int lane = tid & 63;
  const int m0 = blockIdx.y * 128;
  const int n0 = blockIdx.x * 128;

  const int srow = wave * 8 + (lane >> 3);
  const int scol = (lane & 7) * 8;
  const u16* gA = xb + (long long)(m0 + srow) * 512 + scol;
  const u16* gB = WT + (long long)(n0 + srow) * 512 + scol;
  u16* lA = sA + wave * 512;
  u16* lB = sB + wave * 512;

  f32x4 acc[4][4];
#pragma unroll
  for (int i = 0; i < 4; ++i)
#pragma unroll
    for (int j = 0; j < 4; ++j) {
      f32x4 z = {0.f, 0.f, 0.f, 0.f};
      acc[i][j] = z;
    }

  const int wm  = (wave & 1) * 64;
  const int wn  = (wave >> 1) * 64;
  const int l15 = lane & 15;
  const int qk  = (lane >> 4) * 8;

  for (int k0 = 0; k0 < 512; k0 += 64) {
#pragma unroll
    for (int r = 0; r < 4; ++r) {
      glds16(gA + (long long)(r * 32) * 512 + k0, lA + r * 2048);
      glds16(gB + (long long)(r * 32) * 512 + k0, lB + r * 2048);
    }
    __syncthreads();
#pragma unroll
    for (int kk = 0; kk < 64; kk += 32) {
      bf16x8 af[4], bg[4];
#pragma unroll
      for (int mt = 0; mt < 4; ++mt)
        af[mt] = *(const bf16x8*)(sA + (wm + mt * 16 + l15) * 64 + kk + qk);
#pragma unroll
      for (int nt = 0; nt < 4; ++nt)
        bg[nt] = *(const bf16x8*)(sB + (wn + nt * 16 + l15) * 64 + kk + qk);
#pragma unroll
      for (int mt = 0; mt < 4; ++mt)
#pragma unroll
        for (int nt = 0; nt < 4; ++nt)
          acc[mt][nt] = __builtin_amdgcn_mfma_f32_16x16x32_bf16(
              af[mt], bg[nt], acc[mt][nt], 0, 0, 0);
    }
    __syncthreads();
  }

  // C/D layout: col = lane&15, row = (lane>>4)*4 + reg
  const int rowq = (lane >> 4) * 4;
  const int route = n0 >> 9;                 // block-uniform (128 | 512)
  const float* bp = (route == 0) ? bq : (route == 1) ? bk : bv;
#pragma unroll
  for (int nt = 0; nt < 4; ++nt) {
    const int gn = n0 + wn + nt * 16 + l15;
    const int ln = gn & 511;
    const float bval = bp[ln];
#pragma unroll
    for (int mt = 0; mt < 4; ++mt) {
      const int gm = m0 + wm + mt * 16 + rowq;
      if (route == 2) {
        const int b = gm >> 11;
        const int i = gm & (NN - 1);
        ushort4 pk;
        pk.x = f2b(acc[mt][nt][0] + bval);
        pk.y = f2b(acc[mt][nt][1] + bval);
        pk.z = f2b(acc[mt][nt][2] + bval);
        pk.w = f2b(acc[mt][nt][3] + bval);
        *(ushort4*)(&VTb[((long long)b * DD + ln) * NN + i]) = pk;
      } else {
        u16* Cb = (route == 0) ? Qb : Kb;
#pragma unroll
        for (int r = 0; r < 4; ++r)
          Cb[(long long)(gm + r) * DD + ln] = f2b(acc[mt][nt][r] + bval);
      }
    }
  }
}

// ---------------------------------------------------------------------------
// S GEMM + fused column stats: Sb[b][i][j] = bf16(scale * Q[i].K[j]);
// per-block partial column max/sumexp -> pm/pl[b][16 mblocks][2048].
// grid (16 n, 16 m, 8 b).
// ---------------------------------------------------------------------------
__global__ __launch_bounds__(256, 2)
void gemm_s(const u16* __restrict__ Qb, const u16* __restrict__ Kb,
            u16* __restrict__ Sb, float* __restrict__ pm, float* __restrict__ pl,
            float alpha)
{
  __shared__ __align__(16) u16 sA[128 * 64];
  __shared__ __align__(16) u16 sB[128 * 64];
  const int tid  = threadIdx.x;
  const int wave = tid >> 6;
  const int lane = tid & 63;
  const int m0 = blockIdx.y * 128;
  const int n0 = blockIdx.x * 128;
  const long long bz = blockIdx.z;
  const u16* A  = Qb + bz * (long long)NN * DD;
  const u16* Bt = Kb + bz * (long long)NN * DD;
  u16* S = Sb + bz * (long long)NN * NN;

  const int srow = wave * 8 + (lane >> 3);
  const int scol = (lane & 7) * 8;
  const u16* gA = A  + (long long)(m0 + srow) * DD + scol;
  const u16* gB = Bt + (long long)(n0 + srow) * DD + scol;
  u16* lA = sA + wave * 512;
  u16* lB = sB + wave * 512;

  f32x4 acc[4][4];
#pragma unroll
  for (int i = 0; i < 4; ++i)
#pragma unroll
    for (int j = 0; j < 4; ++j) {
      f32x4 z = {0.f, 0.f, 0.f, 0.f};
      acc[i][j] = z;
    }

  const int wm  = (wave & 1) * 64;
  const int wn  = (wave >> 1) * 64;
  const int l15 = lane & 15;
  const int qk  = (lane >> 4) * 8;

  for (int k0 = 0; k0 < DD; k0 += 64) {
#pragma unroll
    for (int r = 0; r < 4; ++r) {
      glds16(gA + (long long)(r * 32) * DD + k0, lA + r * 2048);
      glds16(gB + (long long)(r * 32) * DD + k0, lB + r * 2048);
    }
    __syncthreads();
#pragma unroll
    for (int kk = 0; kk < 64; kk += 32) {
      bf16x8 af[4], bg[4];
#pragma unroll
      for (int mt = 0; mt < 4; ++mt)
        af[mt] = *(const bf16x8*)(sA + (wm + mt * 16 + l15) * 64 + kk + qk);
#pragma unroll
      for (int nt = 0; nt < 4; ++nt)
        bg[nt] = *(const bf16x8*)(sB + (wn + nt * 16 + l15) * 64 + kk + qk);
#pragma unroll
      for (int mt = 0; mt < 4; ++mt)
#pragma unroll
        for (int nt = 0; nt < 4; ++nt)
          acc[mt][nt] = __builtin_amdgcn_mfma_f32_16x16x32_bf16(
              af[mt], bg[nt], acc[mt][nt], 0, 0, 0);
    }
    __syncthreads();
  }

  const int rowq = (lane >> 4) * 4;
  float colm[4], coll[4];
#pragma unroll
  for (int nt = 0; nt < 4; ++nt) {
    float s[16];
#pragma unroll
    for (int mt = 0; mt < 4; ++mt)
#pragma unroll
      for (int r = 0; r < 4; ++r)
        s[mt * 4 + r] = acc[mt][nt][r] * alpha;
    // per-column (wave-level) max over the wave's 64 rows
    float mx = s[0];
#pragma unroll
    for (int k = 1; k < 16; ++k) mx = fmaxf(mx, s[k]);
    mx = fmaxf(mx, __shfl_xor(mx, 16));
    mx = fmaxf(mx, __shfl_xor(mx, 32));
    float sum = 0.f;
#pragma unroll
    for (int k = 0; k < 16; ++k) sum += __expf(s[k] - mx);
    sum += __shfl_xor(sum, 16);
    sum += __shfl_xor(sum, 32);
    colm[nt] = mx; coll[nt] = sum;
    // store bf16 S
    const int gn = n0 + wn + nt * 16 + l15;
#pragma unroll
    for (int mt = 0; mt < 4; ++mt)
#pragma unroll
      for (int r = 0; r < 4; ++r)
        S[(long long)(m0 + wm + mt * 16 + rowq + r) * NN + gn] = f2b(s[mt * 4 + r]);
  }

  // merge wave pairs (same wn, wm 0/64) via LDS; then write block partials
  float* sred = (float*)sA;   // 128 cols x {m0,l0,m1,l1}
  if (lane < 16) {
#pragma unroll
    for (int nt = 0; nt < 4; ++nt) {
      const int col = wn + nt * 16 + l15;
      sred[col * 4 + (wave & 1) * 2]     = colm[nt];
      sred[col * 4 + (wave & 1) * 2 + 1] = coll[nt];
    }
  }
  __syncthreads();
  if (tid < 128) {
    const float m0v = sred[tid * 4],     l0v = sred[tid * 4 + 1];
    const float m1v = sred[tid * 4 + 2], l1v = sred[tid * 4 + 3];
    const float mm = fmaxf(m0v, m1v);
    const float ll = l0v * __expf(m0v - mm) + l1v * __expf(m1v - mm);
    const long long o = ((long long)bz * 16 + blockIdx.y) * NN + n0 + tid;
    pm[o] = mm;
    pl[o] = ll;
  }
}

// ---------------------------------------------------------------------------
// bf16 TN GEMM (PV): C f32. 128x128 tile, BK=64. Batched via z.
// ---------------------------------------------------------------------------
__global__ __launch_bounds__(256, 2)
void gemm_pv(const u16* __restrict__ A, const u16* __restrict__ Bt,
             float* __restrict__ C, int N, int K,
             long long sAb, long long sBb, long long sCb)
{
  __shared__ __align__(16) u16 sA[128 * 64];
  __shared__ __align__(16) u16 sB[128 * 64];
  const int tid  = threadIdx.x;
  const int wave = tid >> 6;
  const int lane = tid & 63;
  const int m0 = blockIdx.y * 128;
  const int n0 = blockIdx.x * 128;
  const long long bz = blockIdx.z;
  A  += bz * sAb;
  Bt += bz * sBb;
  C  += bz * sCb;

  const int srow = wave * 8 + (lane >> 3);
  const int scol = (lane & 7) * 8;
  const u16* gA = A  + (long long)(m0 + srow) * K + scol;
  const u16* gB = Bt + (long long)(n0 + srow) * K + scol;
  u16* lA = sA + wave * 512;
  u16* lB = sB + wave * 512;

  f32x4 acc[4][4];
#pragma unroll
  for (int i = 0; i < 4; ++i)
#pragma unroll
    for (int j = 0; j < 4; ++j) {
      f32x4 z = {0.f, 0.f, 0.f, 0.f};
      acc[i][j] = z;
    }

  const int wm  = (wave & 1) * 64;
  const int wn  = (wave >> 1) * 64;
  const int l15 = lane & 15;
  const int qk  = (lane >> 4) * 8;

  for (int k0 = 0; k0 < K; k0 += 64) {
#pragma unroll
    for (int r = 0; r < 4; ++r) {
      glds16(gA + (long long)(r * 32) * K + k0, lA + r * 2048);
      glds16(gB + (long long)(r * 32) * K + k0, lB + r * 2048);
    }
    __syncthreads();
#pragma unroll
    for (int kk = 0; kk < 64; kk += 32) {
      bf16x8 af[4], bg[4];
#pragma unroll
      for (int mt = 0; mt < 4; ++mt)
        af[mt] = *(const bf16x8*)(sA + (wm + mt * 16 + l15) * 64 + kk + qk);
#pragma unroll
      for (int nt = 0; nt < 4; ++nt)
        bg[nt] = *(const bf16x8*)(sB + (wn + nt * 16 + l15) * 64 + kk + qk);
#pragma unroll
      for (int mt = 0; mt < 4; ++mt)
#pragma unroll
        for (int nt = 0; nt < 4; ++nt)
          acc[mt][nt] = __builtin_amdgcn_mfma_f32_16x16x32_bf16(
              af[mt], bg[nt], acc[mt][nt], 0, 0, 0);
    }
    __syncthreads();
  }

  const int rowq = (lane >> 4) * 4;
#pragma unroll
  for (int nt = 0; nt < 4; ++nt) {
    const int gn = n0 + wn + nt * 16 + l15;
#pragma unroll
    for (int mt = 0; mt < 4; ++mt) {
#pragma unroll
      for (int r = 0; r < 4; ++r) {
        const int gm = m0 + wm + mt * 16 + rowq + r;
        C[(long long)gm * N + gn] = acc[mt][nt][r];
      }
    }
  }
}

// ---------------------------------------------------------------------------
// f32 -> bf16 bulk convert (x)
// ---------------------------------------------------------------------------
__global__ __launch_bounds__(256)
void conv_f32_bf16(const float* __restrict__ in, u16* __restrict__ out)
{
  const long long i = ((long long)blockIdx.x * 256 + threadIdx.x) * 4;
  const float4 v = *(const float4*)(in + i);
  ushort4 o;
  o.x = f2b(v.x); o.y = f2b(v.y); o.z = f2b(v.z); o.w = f2b(v.w);
  *(ushort4*)(out + i) = o;
}

// ---------------------------------------------------------------------------
// 64x64 transpose + f32->bf16, z selects which weight matrix
// ---------------------------------------------------------------------------
__global__ __launch_bounds__(256)
void transpose_conv3(const float* __restrict__ w0, const float* __restrict__ w1,
                     const float* __restrict__ w2, u16* __restrict__ out)
{
  __shared__ float tile[64][65];
  const int z = blockIdx.z;
  const float* in = (z == 0) ? w0 : (z == 1) ? w1 : w2;
  u16* o = out + (long long)z * 512 * 512;
  const int r0 = blockIdx.y * 64;
  const int c0 = blockIdx.x * 64;
  const int tr = threadIdx.x >> 6;
  const int tc = threadIdx.x & 63;
#pragma unroll
  for (int k = 0; k < 16; ++k) {
    const int r = k * 4 + tr;
    tile[r][tc] = in[(long long)(r0 + r) * 512 + c0 + tc];
  }
  __syncthreads();
#pragma unroll
  for (int k = 0; k < 16; ++k) {
    const int r = k * 4 + tr;
    o[(long long)(c0 + r) * 512 + r0 + tc] = f2b(tile[tc][r]);
  }
}

// ---------------------------------------------------------------------------
// combine block partials -> cst[b][j] = m* + log l*
// ---------------------------------------------------------------------------
__global__ __launch_bounds__(256)
void softmax_combine(const float* __restrict__ pm, const float* __restrict__ pl,
                     float* __restrict__ cst)
{
  const int idx = blockIdx.x * 256 + threadIdx.x;  // b*2048 + j
  const int b = idx >> 11;
  const int j = idx & (NN - 1);
  const float* bm = pm + (long long)b * 16 * NN + j;
  const float* bl = pl + (long long)b * 16 * NN + j;
  float m = -3.4e38f;
#pragma unroll
  for (int t = 0; t < 16; ++t)
    m = fmaxf(m, bm[(long long)t * NN]);
  float l = 0.f;
#pragma unroll
  for (int t = 0; t < 16; ++t)
    l += bl[(long long)t * NN] * __expf(bm[(long long)t * NN] - m);
  cst[idx] = m + __logf(l);
}

// ---------------------------------------------------------------------------
// normalize: read Sb bf16, write Wf f32 (output) + Wb bf16 (for PV)
// ---------------------------------------------------------------------------
__global__ __launch_bounds__(256)
void softmax_normalize(const u16* __restrict__ Sb, float* __restrict__ Wf,
                       u16* __restrict__ Wb, const float* __restrict__ cst)
{
  const long long idx = ((long long)blockIdx.x * 256 + threadIdx.x) * 8;
  const int b  = (int)(idx >> 22);
  const int j0 = (int)(idx & (NN - 1));
  const float* c = cst + b * NN + j0;
  u16x8 v = *(const u16x8*)(Sb + idx);
  float w[8];
#pragma unroll
  for (int k = 0; k < 8; ++k)
    w[k] = __expf(b2f(v[k]) - c[k]);
  float4 o0 = {w[0], w[1], w[2], w[3]};
  float4 o1 = {w[4], w[5], w[6], w[7]};
  *(float4*)(Wf + idx)     = o0;
  *(float4*)(Wf + idx + 4) = o1;
  u16x8 ob;
#pragma unroll
  for (int k = 0; k < 8; ++k) ob[k] = f2b(w[k]);
  *(u16x8*)(Wb + idx) = ob;
}

// ---------------------------------------------------------------------------
extern "C" void kernel_launch(void* const* d_in, const int* in_sizes, int n_in,
                              void* d_out, int out_size, void* d_ws, size_t ws_size,
                              hipStream_t stream)
{
  const float* x  = (const float*)d_in[0];
  const float* Wq = (const float*)d_in[1];
  const float* bq = (const float*)d_in[2];
  const float* Wk = (const float*)d_in[3];
  const float* bk = (const float*)d_in[4];
  const float* Wv = (const float*)d_in[5];
  const float* bv = (const float*)d_in[6];

  float* outf = (float*)d_out;                         // [8][2048][512] f32
  float* Wf   = outf + (long long)BB * NN * DD;        // [8][2048][2048] f32

  // Q/K bf16 scratch inside the f32 out region (dead before PV writes outf)
  u16* Qb = (u16*)d_out;                               // [8][2048][512] bf16
  u16* Kb = Qb + (long long)BB * NN * DD;

  // workspace carve (~172 MiB; ws is ~671 MB per the poison fill)
  u16* Wb  = (u16*)d_ws;                               // [8][2048][2048] bf16
  u16* Sb  = Wb + (long long)BB * NN * NN;             // [8][2048][2048] bf16
  u16* VTb = Sb + (long long)BB * NN * NN;             // [8][512][2048] bf16
  u16* xb  = VTb + (long long)BB * NN * DD;            // [16384][512] bf16
  u16* WT  = xb + (long long)BB * NN * DD;             // [1536][512] bf16
  float* pm  = (float*)(WT + 1536 * 512);              // [8][16][2048]
  float* pl  = pm + (long long)8 * 16 * NN;
  float* cst = pl + (long long)8 * 16 * NN;            // [8][2048]

  dim3 blk(256);

  // x -> bf16; W^T (bf16) concat rows: [0,512)=Wq^T, [512,1024)=Wk^T, [1024,1536)=Wv^T
  conv_f32_bf16<<<dim3(8192), blk, 0, stream>>>(x, xb);
  transpose_conv3<<<dim3(8, 8, 3), blk, 0, stream>>>(Wq, Wk, Wv, WT);

  // fused QKV projection: [16384,512] x [512,1536] + bias
  gemm_qkv<<<dim3(12, 128), blk, 0, stream>>>(xb, WT, bq, bk, bv, Qb, Kb, VTb);

  // S = scale*Q K^T -> bf16 Sb, with fused per-block column stats
  const float scale = 0.044194173824159216f;  // 1/sqrt(512)
  gemm_s<<<dim3(16, 16, 8), blk, 0, stream>>>(Qb, Kb, Sb, pm, pl, scale);

  // column softmax (axis=1): combine partials, then normalize
  softmax_combine<<<dim3(64), blk, 0, stream>>>(pm, pl, cst);
  softmax_normalize<<<dim3(16384), blk, 0, stream>>>(Sb, Wf, Wb, cst);

  // out = weights x V : [2048,2048] x [2048,512] per batch (bf16 operands)
  gemm_pv<<<dim3(4, 16, 8), blk, 0, stream>>>(Wb, VTb, outf, DD, NN,
      (long long)NN * NN, (long long)DD * NN, (long long)NN * DD);
}